// Round 3
// baseline (1307.561 us; speedup 1.0000x reference)
//
#include <hip/hip_runtime.h>
#include <hip/hip_bf16.h>

// Problem: VectorQuantizer. z: [32,256,32,32] f32 NCHW, codebook: [1024,256] f32.
// Outputs (concat f32): z_q_out [32,256,32,32], loss[1], perplexity[1], idx[32768] (as float), mean_distance[1].
// N = 32768 points, K = 1024 codes, D = 256.
// idx must replicate numpy-fp32 argmin of d = fl32(fl32(s_n + t_k) - 2*fl32(dot)).

#define NPTS   32768
#define KCODE  1024
#define DDIM   256
#define HWSZ   1024     // 32*32
#define ZSTRB  262144   // 256*1024 floats per batch
#define ZELEMS 8388608

#define OUT_LOSS 8388608
#define OUT_PERP 8388609
#define OUT_IDX  8388610
#define OUT_MD   8421378

// ws byte offsets
#define WS_IDX     0        // int[32768]
#define WS_COUNTS  131072   // int[1024]
#define WS_RLIST   135168   // int[32768]
#define WS_RCOUNT  266240   // int
#define WS_LOSSSUM 266248   // double
#define WS_ZSQ     266256   // double
#define WS_ENSUM   266264   // double
#define WS_CHSUM   266272   // double[256]
#define WS_ESUM    268320   // double[256]
#define WS_ENORM   270368   // float[1024]  (np-fp32 pairwise ||e_k||^2)
#define WS_CBT     274464   // float[256*1024]  codebook transposed [d][k]

// flip can only happen if exact top-2 gap < 2*ulp(256)+dot_err ~ 6.2e-5; 2x margin
#define MARGIN 1.2e-4f

__global__ __launch_bounds__(256) void init_kernel(char* ws) {
    int t = threadIdx.x;
    int* counts = (int*)(ws + WS_COUNTS);
    for (int i = t; i < 1024; i += 256) counts[i] = 0;
    if (t == 0) *(int*)(ws + WS_RCOUNT) = 0;
    double* dbl = (double*)(ws + WS_LOSSSUM);
    for (int i = t; i < 515; i += 256) dbl[i] = 0.0;  // losssum,zsq,ensum + chsum[256] + esum[256]
}

// fp64 codebook column sums + total norm sum (for closed-form mean_distance)
__global__ __launch_bounds__(256) void prep_kernel(const float* __restrict__ cb,
                                                   double* __restrict__ esum,
                                                   double* __restrict__ enormsum) {
    int t = threadIdx.x;
    int k0 = blockIdx.x * 64;
    __shared__ double red[4];
    double esum_loc = 0.0;
    double ensum_loc = 0.0;
    for (int r = 0; r < 64; ++r) {
        float v = cb[(size_t)(k0 + r) * DDIM + t];
        esum_loc += (double)v;
        double s = (double)v * (double)v;
        for (int o = 32; o; o >>= 1) s += __shfl_down(s, o, 64);
        if ((t & 63) == 0) red[t >> 6] = s;
        __syncthreads();
        if (t == 0) ensum_loc += red[0] + red[1] + red[2] + red[3];
        __syncthreads();
    }
    atomicAdd(&esum[t], esum_loc);
    if (t == 0) atomicAdd(enormsum, ensum_loc);
}

// numpy pairwise fp32 sum of squares of a 256-row, exact tree:
// two 128-blocks (8 strided accumulators, ((r0+r1)+(r2+r3))+((r4+r5)+(r6+r7))), then block0+block1.
// asm barriers stop ffp-contract from fusing square into the add.
__device__ __forceinline__ float np_sumsq256(const float* p) {
    float tot[2];
    #pragma unroll
    for (int h = 0; h < 2; ++h) {
        const float* a = p + h * 128;
        float r[8];
        #pragma unroll
        for (int j = 0; j < 8; ++j) { float v = a[j]; float s = v * v; asm volatile("" : "+v"(s)); r[j] = s; }
        for (int i = 8; i < 128; i += 8) {
            #pragma unroll
            for (int j = 0; j < 8; ++j) { float v = a[i + j]; float s = v * v; asm volatile("" : "+v"(s)); r[j] += s; }
        }
        tot[h] = ((r[0] + r[1]) + (r[2] + r[3])) + ((r[4] + r[5]) + (r[6] + r[7]));
    }
    return tot[0] + tot[1];
}

// per-code: np-fp32 t_k and transposed codebook cbT[d][k]
__global__ __launch_bounds__(256) void prep2_kernel(const float* __restrict__ cb,
                                                    float* __restrict__ enorm,
                                                    float* __restrict__ cbT) {
    int k = blockIdx.x * 256 + threadIdx.x;   // 4 blocks
    const float* row = cb + (size_t)k * DDIM;
    enorm[k] = np_sumsq256(row);
    for (int d = 0; d < DDIM; ++d) cbT[d * KCODE + k] = row[d];
}

// Phase 1: per-point argmin screen over criterion t_k - 2 z.e_k (fp32).
// 64 points/block in swizzled LDS; 4 waves each own a 256-code quarter; 4 codes/pass.
// LDS layout: element (point p, channel d) at byte (p<<10) | ((d<<2) ^ ((p&31)<<4)).
__global__ __launch_bounds__(256) void argmin_kernel(const float* __restrict__ z,
                                                     const float* __restrict__ cb,
                                                     const float* __restrict__ enorm,
                                                     int* __restrict__ ws_idx,
                                                     int* __restrict__ rlist,
                                                     int* __restrict__ rcount) {
    __shared__ float tile[64 * DDIM];   // [p][d], XOR-swizzled
    __shared__ float rbest[4][64];
    __shared__ float rsec[4][64];
    __shared__ int   ridx[4][64];

    int tid = threadIdx.x;
    int n0 = blockIdx.x * 64;
    int b = n0 >> 10, hw0 = n0 & 1023;
    const float* zb = z + (size_t)b * ZSTRB;

    // stage: 4096 float4s; coalesced global reads, swizzled scalar LDS stores
    char* tb = (char*)tile;
    for (int i = 0; i < 16; ++i) {
        int f  = tid + 256 * i;        // float4 index: 4 points (p4..p4+3) at channel d
        int d  = f >> 4;               // channel 0..255
        int p4 = (f & 15) << 2;        // point base 0..60
        const float4 v = *(const float4*)(zb + d * HWSZ + hw0 + p4);
        { int p = p4 + 0; int off = (p << 10) | ((d << 2) ^ ((p & 31) << 4)); *(float*)(tb + off) = v.x; }
        { int p = p4 + 1; int off = (p << 10) | ((d << 2) ^ ((p & 31) << 4)); *(float*)(tb + off) = v.y; }
        { int p = p4 + 2; int off = (p << 10) | ((d << 2) ^ ((p & 31) << 4)); *(float*)(tb + off) = v.z; }
        { int p = p4 + 3; int off = (p << 10) | ((d << 2) ^ ((p & 31) << 4)); *(float*)(tb + off) = v.w; }
    }
    __syncthreads();

    int p = tid & 63, g = tid >> 6;
    float best = 3.4e38f, sec = 3.4e38f;
    int bidx = 0;
    int rowbase = (p << 10);
    int swz = (p & 31) << 4;

    for (int kb = 0; kb < 256; kb += 4) {
        int k = __builtin_amdgcn_readfirstlane((g << 8) + kb);
        const float4* e0 = (const float4*)(cb + (size_t)k * DDIM);
        const float4* e1 = e0 + 64;
        const float4* e2 = e0 + 128;
        const float4* e3 = e0 + 192;
        float a0 = 0.f, a1 = 0.f, a2 = 0.f, a3 = 0.f;
        #pragma unroll 4
        for (int d4 = 0; d4 < 64; ++d4) {
            float4 zv = *(const float4*)(tb + (rowbase | ((d4 << 4) ^ swz)));
            float4 q0 = e0[d4], q1 = e1[d4], q2 = e2[d4], q3 = e3[d4];
            a0 = fmaf(zv.x, q0.x, a0); a0 = fmaf(zv.y, q0.y, a0);
            a0 = fmaf(zv.z, q0.z, a0); a0 = fmaf(zv.w, q0.w, a0);
            a1 = fmaf(zv.x, q1.x, a1); a1 = fmaf(zv.y, q1.y, a1);
            a1 = fmaf(zv.z, q1.z, a1); a1 = fmaf(zv.w, q1.w, a1);
            a2 = fmaf(zv.x, q2.x, a2); a2 = fmaf(zv.y, q2.y, a2);
            a2 = fmaf(zv.z, q2.z, a2); a2 = fmaf(zv.w, q2.w, a2);
            a3 = fmaf(zv.x, q3.x, a3); a3 = fmaf(zv.y, q3.y, a3);
            a3 = fmaf(zv.z, q3.z, a3); a3 = fmaf(zv.w, q3.w, a3);
        }
        float c0 = fmaf(-2.f, a0, enorm[k + 0]);
        float c1 = fmaf(-2.f, a1, enorm[k + 1]);
        float c2 = fmaf(-2.f, a2, enorm[k + 2]);
        float c3 = fmaf(-2.f, a3, enorm[k + 3]);
        if (c0 < best) { sec = best; best = c0; bidx = k + 0; } else if (c0 < sec) sec = c0;
        if (c1 < best) { sec = best; best = c1; bidx = k + 1; } else if (c1 < sec) sec = c1;
        if (c2 < best) { sec = best; best = c2; bidx = k + 2; } else if (c2 < sec) sec = c2;
        if (c3 < best) { sec = best; best = c3; bidx = k + 3; } else if (c3 < sec) sec = c3;
    }

    rbest[g][p] = best; rsec[g][p] = sec; ridx[g][p] = bidx;
    __syncthreads();

    if (tid < 64) {
        float B = rbest[0][p]; int I = ridx[0][p]; float S = rsec[0][p];
        #pragma unroll
        for (int gg = 1; gg < 4; ++gg) {
            float b2 = rbest[gg][p], s2 = rsec[gg][p];
            if (b2 < B) { S = fminf(B, s2); I = ridx[gg][p]; B = b2; }
            else        { S = fminf(S, b2); }
        }
        int n = n0 + p;
        ws_idx[n] = I;
        if (S - B < MARGIN) {
            int slot = atomicAdd(rcount, 1);
            if (slot < NPTS) rlist[slot] = n;
        }
    }
}

// Recheck flagged points replicating numpy fp32 semantics:
// d(k) = fl32( fl32(s_n + t_k) - 2*fl32(dot64(z,e_k)) ), argmin with first-index tiebreak.
__global__ __launch_bounds__(256) void recheck_kernel(const float* __restrict__ z,
                                                      const float* __restrict__ cbT,
                                                      const float* __restrict__ enorm,
                                                      int* __restrict__ ws_idx,
                                                      const int* __restrict__ rlist,
                                                      const int* __restrict__ rcount) {
    __shared__ float zs[DDIM];
    __shared__ float s_sh;
    __shared__ float bv[256];
    __shared__ int   bi[256];
    int t = threadIdx.x;
    int cnt = *rcount; if (cnt > NPTS) cnt = NPTS;
    for (int it = blockIdx.x; it < cnt; it += gridDim.x) {
        int n = rlist[it];
        int b = n >> 10, hw = n & 1023;
        zs[t] = z[(size_t)b * ZSTRB + (size_t)t * HWSZ + hw];
        __syncthreads();
        if (t == 0) s_sh = np_sumsq256(zs);   // numpy pairwise fp32 ||z_n||^2
        __syncthreads();
        float s_n = s_sh;
        float best = 3.4e38f; int bidx = 0;
        #pragma unroll
        for (int j = 0; j < 4; ++j) {
            int k = t + 256 * j;
            double dot = 0.0;
            for (int d = 0; d < DDIM; ++d)
                dot = fma((double)cbT[d * KCODE + k], (double)zs[d], dot);
            float E = (float)dot;            // einsum's fp32 value (to ~3e-9)
            float w = 2.0f * E;              // exact x2
            float u = s_n + enorm[k];        // fp32 add
            float dd = u - w;                // fp32 sub
            if (dd < best) { best = dd; bidx = k; }   // j ascending => lowest k kept
        }
        bv[t] = best; bi[t] = bidx;
        __syncthreads();
        for (int s2 = 128; s2; s2 >>= 1) {
            if (t < s2) {
                if (bv[t + s2] < bv[t] || (bv[t + s2] == bv[t] && bi[t + s2] < bi[t])) {
                    bv[t] = bv[t + s2]; bi[t] = bi[t + s2];
                }
            }
            __syncthreads();
        }
        if (t == 0) ws_idx[n] = bi[0];
        __syncthreads();
    }
}

// histogram + idx-as-float output
__global__ __launch_bounds__(256) void hist_kernel(const int* __restrict__ ws_idx,
                                                   int* __restrict__ counts,
                                                   float* __restrict__ out_idx) {
    __shared__ int h[KCODE];
    int t = threadIdx.x;
    for (int i = t; i < KCODE; i += 256) h[i] = 0;
    __syncthreads();
    int n = blockIdx.x * 256 + t;
    int idx = ws_idx[n];
    out_idx[n] = (float)idx;
    atomicAdd(&h[idx], 1);
    __syncthreads();
    for (int i = t; i < KCODE; i += 256) { int c = h[i]; if (c) atomicAdd(&counts[i], c); }
}

// z_q_out (straight-through rounding replicated) + loss sum + z channel sums + z^2 total
__global__ __launch_bounds__(256) void out_kernel(const float* __restrict__ z,
                                                  const float* __restrict__ cb,
                                                  const int* __restrict__ ws_idx,
                                                  float* __restrict__ out,
                                                  double* __restrict__ lossSum,
                                                  double* __restrict__ chsum,
                                                  double* __restrict__ zsq) {
    int t = threadIdx.x;
    size_t base = (size_t)blockIdx.x * 1024;
    int c = blockIdx.x & 255;          // channel, constant per block
    int b = blockIdx.x >> 8;
    int hw = t * 4;
    const float4 zv = *(const float4*)(z + base + hw);
    int4 iv = *(const int4*)(ws_idx + b * HWSZ + hw);
    float q0 = cb[(size_t)iv.x * DDIM + c];
    float q1 = cb[(size_t)iv.y * DDIM + c];
    float q2 = cb[(size_t)iv.z * DDIM + c];
    float q3 = cb[(size_t)iv.w * DDIM + c];
    float t0 = q0 - zv.x, t1 = q1 - zv.y, t2 = q2 - zv.z, t3 = q3 - zv.w;
    float4 o; o.x = zv.x + t0; o.y = zv.y + t1; o.z = zv.z + t2; o.w = zv.w + t3;
    *(float4*)(out + base + hw) = o;

    double ls  = (double)t0 * t0 + (double)t1 * t1 + (double)t2 * t2 + (double)t3 * t3;
    double zs  = (double)zv.x + (double)zv.y + (double)zv.z + (double)zv.w;
    double zq2 = (double)zv.x * zv.x + (double)zv.y * zv.y + (double)zv.z * zv.z + (double)zv.w * zv.w;

    __shared__ double r1[4], r2[4], r3[4];
    for (int o2 = 32; o2; o2 >>= 1) {
        ls  += __shfl_down(ls,  o2, 64);
        zs  += __shfl_down(zs,  o2, 64);
        zq2 += __shfl_down(zq2, o2, 64);
    }
    if ((t & 63) == 0) { int w = t >> 6; r1[w] = ls; r2[w] = zs; r3[w] = zq2; }
    __syncthreads();
    if (t == 0) {
        atomicAdd(lossSum, r1[0] + r1[1] + r1[2] + r1[3]);
        atomicAdd(&chsum[c], r2[0] + r2[1] + r2[2] + r2[3]);
        atomicAdd(zsq, r3[0] + r3[1] + r3[2] + r3[3]);
    }
}

__global__ __launch_bounds__(256) void fin_kernel(const int* __restrict__ counts,
                                                  const double* __restrict__ lossSum,
                                                  const double* __restrict__ chsum,
                                                  const double* __restrict__ esum,
                                                  const double* __restrict__ zsq,
                                                  const double* __restrict__ enormsum,
                                                  float* __restrict__ out) {
    int t = threadIdx.x;
    double ent = 0.0;
    for (int i = t; i < KCODE; i += 256) {
        float em = (float)counts[i] / 32768.0f;
        ent += (double)(em * logf(em + 1e-10f));
    }
    double pd = chsum[t] * esum[t];

    __shared__ double r1[4], r2[4];
    for (int o2 = 32; o2; o2 >>= 1) {
        ent += __shfl_down(ent, o2, 64);
        pd  += __shfl_down(pd,  o2, 64);
    }
    if ((t & 63) == 0) { int w = t >> 6; r1[w] = ent; r2[w] = pd; }
    __syncthreads();
    if (t == 0) {
        double ENT = r1[0] + r1[1] + r1[2] + r1[3];
        double PD  = r2[0] + r2[1] + r2[2] + r2[3];
        float m = (float)(*lossSum / (double)ZELEMS);
        out[OUT_LOSS] = 0.25f * m + m;
        out[OUT_PERP] = expf((float)(-ENT));
        double md = *zsq / (double)NPTS + *enormsum / (double)KCODE
                    - (2.0 / ((double)NPTS * (double)KCODE)) * PD;
        out[OUT_MD] = (float)md;
    }
}

extern "C" void kernel_launch(void* const* d_in, const int* in_sizes, int n_in,
                              void* d_out, int out_size, void* d_ws, size_t ws_size,
                              hipStream_t stream) {
    const float* z  = (const float*)d_in[0];
    const float* cb = (const float*)d_in[1];
    float* out = (float*)d_out;
    char* ws = (char*)d_ws;

    int*    ws_idx   = (int*)(ws + WS_IDX);
    int*    counts   = (int*)(ws + WS_COUNTS);
    int*    rlist    = (int*)(ws + WS_RLIST);
    int*    rcount   = (int*)(ws + WS_RCOUNT);
    double* lossSum  = (double*)(ws + WS_LOSSSUM);
    double* zsq      = (double*)(ws + WS_ZSQ);
    double* enormsum = (double*)(ws + WS_ENSUM);
    double* chsum    = (double*)(ws + WS_CHSUM);
    double* esum     = (double*)(ws + WS_ESUM);
    float*  enorm    = (float*)(ws + WS_ENORM);
    float*  cbT      = (float*)(ws + WS_CBT);

    hipLaunchKernelGGL(init_kernel, dim3(1), dim3(256), 0, stream, ws);
    hipLaunchKernelGGL(prep_kernel, dim3(16), dim3(256), 0, stream, cb, esum, enormsum);
    hipLaunchKernelGGL(prep2_kernel, dim3(4), dim3(256), 0, stream, cb, enorm, cbT);
    hipLaunchKernelGGL(argmin_kernel, dim3(512), dim3(256), 0, stream,
                       z, cb, enorm, ws_idx, rlist, rcount);
    hipLaunchKernelGGL(recheck_kernel, dim3(64), dim3(256), 0, stream,
                       z, cbT, enorm, ws_idx, rlist, rcount);
    hipLaunchKernelGGL(hist_kernel, dim3(128), dim3(256), 0, stream,
                       ws_idx, counts, out + OUT_IDX);
    hipLaunchKernelGGL(out_kernel, dim3(8192), dim3(256), 0, stream,
                       z, cb, ws_idx, out, lossSum, chsum, zsq);
    hipLaunchKernelGGL(fin_kernel, dim3(1), dim3(256), 0, stream,
                       counts, lossSum, chsum, esum, zsq, enormsum, out);
}